// Round 1
// baseline (34547.418 us; speedup 1.0000x reference)
//
#include <hip/hip_runtime.h>
#include <math.h>

// Problem dims
#define BB 64
#define TT 512
#define DD 256
#define HH 1024
#define GG 4096  // 4*H

typedef __bf16 bf16x8 __attribute__((ext_vector_type(8)));
typedef float floatx4 __attribute__((ext_vector_type(4)));

// ---------------- fp32 -> bf16 conversion (weights) ----------------
__global__ void cvt_bf16_kernel(const float* __restrict__ src,
                                __bf16* __restrict__ dst, int n) {
    int i = (blockIdx.x * blockDim.x + threadIdx.x) * 8;
    if (i >= n) return;
    float4 a = *(const float4*)(src + i);
    float4 b = *(const float4*)(src + i + 4);
    bf16x8 v;
    v[0] = (__bf16)a.x; v[1] = (__bf16)a.y; v[2] = (__bf16)a.z; v[3] = (__bf16)a.w;
    v[4] = (__bf16)b.x; v[5] = (__bf16)b.y; v[6] = (__bf16)b.z; v[7] = (__bf16)b.w;
    *(bf16x8*)(dst + i) = v;
}

// ---------------- init: combined bias, zero barrier flags ----------------
__global__ void init_misc_kernel(const float* __restrict__ bx,
                                 const float* __restrict__ bh,
                                 float* __restrict__ bc,
                                 unsigned* __restrict__ flags) {
    int i = blockIdx.x * blockDim.x + threadIdx.x;
    if (i < GG) bc[i] = bx[i] + bh[i];
    if (i < 1024) flags[i] = 0u;   // 256 x 16B-padded flag slots
}

// ---------------- persistent LSTM over all T timesteps ----------------
// One cooperative launch: 256 blocks (j-tile of 4) x 256 threads (4 waves).
// W tile (16 packed gate rows x 1280 K) staged in LDS ONCE, reused 512x.
// Cell state lives in a register of its owning epilogue thread.
// h_t exchanged via bf16 ping-pong in global; custom flag grid barrier per step.
__global__ __launch_bounds__(256) void lstm_seq_kernel(
    const float* __restrict__ x,      // (B,T,D) fp32
    const __bf16* __restrict__ Wxb,   // (4096,256) bf16
    const __bf16* __restrict__ Whb,   // (4096,1024) bf16
    const float* __restrict__ bc,     // (4096) combined bias
    float* __restrict__ hs,           // (B,T,H) fp32 raw h (d_out hidden region)
    __bf16* __restrict__ hping,       // 2 x (B*H) bf16 ping-pong h
    unsigned* __restrict__ flags) {   // 256 x 4 uints (16B stride), zeroed
    __shared__ __bf16 W_s[16][1288];
    __shared__ float gate_s[64][17];

    const int tid = threadIdx.x;
    const int bid = blockIdx.x;
    const int j0 = bid * 4;

    // Stage [Wx | Wh] rows for the 16 packed gate rows (ONCE).
    for (int ch = tid; ch < 2560; ch += 256) {
        int r = ch / 160;
        int pos = ch - r * 160;
        int k = pos * 8;
        int gate = r >> 2;
        int jr = r & 3;
        int gr = gate * HH + j0 + jr;
        const __bf16* src = (k < DD) ? (Wxb + (size_t)gr * DD + k)
                                     : (Whb + (size_t)gr * HH + (k - DD));
        *(uint4*)(&W_s[r][k]) = *(const uint4*)src;
    }

    const int wave = tid >> 6;
    const int lane = tid & 63;
    const int ln = lane & 15;   // A row (b within wave tile) AND B row (packed gate)
    const int q = lane >> 4;    // k-quad
    const int brow = wave * 16 + ln;

    // epilogue thread -> (b, jj); fixed for the whole sequence
    const int b2 = tid >> 2;
    const int jj = tid & 3;
    const int j = j0 + jj;
    const float bci = bc[j];
    const float bcf = bc[HH + j];
    const float bcg = bc[2 * HH + j];
    const float bco = bc[3 * HH + j];
    float creg = 0.0f;          // cell state, register-resident

    __syncthreads();            // W_s ready

    for (int t = 0; t < TT; ++t) {
        floatx4 acc = {0.f, 0.f, 0.f, 0.f};

        // x part: K = 0..255 (convert fp32 -> bf16 in-lane)
        {
            const float* xrow = x + ((size_t)brow * TT + t) * DD;
#pragma unroll
            for (int k0 = 0; k0 < DD; k0 += 32) {
                int ka = k0 + q * 8;
                float4 f0 = *(const float4*)(xrow + ka);
                float4 f1 = *(const float4*)(xrow + ka + 4);
                bf16x8 av;
                av[0] = (__bf16)f0.x; av[1] = (__bf16)f0.y;
                av[2] = (__bf16)f0.z; av[3] = (__bf16)f0.w;
                av[4] = (__bf16)f1.x; av[5] = (__bf16)f1.y;
                av[6] = (__bf16)f1.z; av[7] = (__bf16)f1.w;
                bf16x8 bv = *(const bf16x8*)(&W_s[ln][ka]);
                acc = __builtin_amdgcn_mfma_f32_16x16x32_bf16(av, bv, acc, 0, 0, 0);
            }
        }

        // h part: K = 256..1279, h_{t-1} from bf16 ping-pong buffer (zero at t=0)
        if (t > 0) {
            const __bf16* hrow =
                hping + (size_t)((t - 1) & 1) * (BB * HH) + (size_t)brow * HH;
#pragma unroll 8
            for (int k0 = 0; k0 < HH; k0 += 32) {
                int ka = k0 + q * 8;
                bf16x8 av = *(const bf16x8*)(hrow + ka);
                bf16x8 bv = *(const bf16x8*)(&W_s[ln][DD + ka]);
                acc = __builtin_amdgcn_mfma_f32_16x16x32_bf16(av, bv, acc, 0, 0, 0);
            }
        }

        // C[row=(q*4+r)][col=ln] -> LDS so each thread can gather its 4 gates
#pragma unroll
        for (int r = 0; r < 4; ++r)
            gate_s[wave * 16 + q * 4 + r][ln] = acc[r];
        __syncthreads();

        float iv = gate_s[b2][jj]      + bci;
        float fv = gate_s[b2][4 + jj]  + bcf;
        float gv = gate_s[b2][8 + jj]  + bcg;
        float ov = gate_s[b2][12 + jj] + bco;
        iv = 1.f / (1.f + expf(-iv));
        fv = 1.f / (1.f + expf(-fv));
        gv = 1.f / (1.f + expf(-gv));   // reference sigmoids the cell gate too
        ov = 1.f / (1.f + expf(-ov));
        creg = creg * fv + iv * gv;
        float hh = ov * tanhf(creg);
        hs[((size_t)b2 * TT + t) * HH + j] = hh;                         // raw h fp32
        hping[(size_t)(t & 1) * (BB * HH) + (size_t)b2 * HH + j] = (__bf16)hh;

        if (t == TT - 1) break;   // no barrier needed after last step

        // ---- grid barrier: release h_t, wait for all blocks ----
        __threadfence();          // agent-scope release (wbl2: cross-XCD visible)
        __syncthreads();          // all threads' stores+fences done
        if (tid == 0)
            __hip_atomic_store(flags + bid * 4, (unsigned)(t + 1),
                               __ATOMIC_RELEASE, __HIP_MEMORY_SCOPE_AGENT);
        if (tid < 64) {           // wave 0 polls all 256 block flags
            const unsigned target = (unsigned)(t + 1);
            bool ready;
            do {
                ready = true;
#pragma unroll
                for (int s = 0; s < 4; ++s) {
                    unsigned v = __hip_atomic_load(flags + (s * 64 + tid) * 4,
                                                   __ATOMIC_RELAXED,
                                                   __HIP_MEMORY_SCOPE_AGENT);
                    ready = ready && (v >= target);
                }
                if (!ready) __builtin_amdgcn_s_sleep(2);
            } while (!__all((int)ready));
        }
        __syncthreads();          // fan-out
        __threadfence();          // agent-scope acquire (inv: drop stale L2 lines)
    }
}

// ---------------- output head: out = hs @ Wout^T + bout ----------------
// grid: (D/16, B*T/64); block tile 64 rows x 16 d-cols, K = 1024
__global__ __launch_bounds__(256) void out_gemm_kernel(
    const float* __restrict__ hs,    // (B*T, H) raw fp32
    const __bf16* __restrict__ Wob,  // (D, H) bf16
    const float* __restrict__ bout,  // (D)
    float* __restrict__ out) {       // (B*T, D)
    __shared__ __bf16 Wout_s[16][1032];
    const int tid = threadIdx.x;
    const int d0 = blockIdx.x * 16;
    const int row0 = blockIdx.y * 64;

    for (int ch = tid; ch < 2048; ch += 256) {
        int r = ch >> 7;
        int k = (ch & 127) * 8;
        *(uint4*)(&Wout_s[r][k]) = *(const uint4*)(Wob + (size_t)(d0 + r) * HH + k);
    }
    __syncthreads();

    const int wave = tid >> 6;
    const int lane = tid & 63;
    const int ln = lane & 15;
    const int q = lane >> 4;
    const int row = row0 + wave * 16 + ln;

    const float* arow = hs + (size_t)row * HH;
    floatx4 acc = {0.f, 0.f, 0.f, 0.f};
#pragma unroll 8
    for (int k0 = 0; k0 < HH; k0 += 32) {
        int ka = k0 + q * 8;
        float4 f0 = *(const float4*)(arow + ka);
        float4 f1 = *(const float4*)(arow + ka + 4);
        bf16x8 av;
        av[0] = (__bf16)f0.x; av[1] = (__bf16)f0.y;
        av[2] = (__bf16)f0.z; av[3] = (__bf16)f0.w;
        av[4] = (__bf16)f1.x; av[5] = (__bf16)f1.y;
        av[6] = (__bf16)f1.z; av[7] = (__bf16)f1.w;
        bf16x8 bv = *(const bf16x8*)(&Wout_s[ln][ka]);
        acc = __builtin_amdgcn_mfma_f32_16x16x32_bf16(av, bv, acc, 0, 0, 0);
    }
    float bo = bout[d0 + ln];
    const int orow0 = row0 + wave * 16 + q * 4;
#pragma unroll
    for (int r = 0; r < 4; ++r)
        out[(size_t)(orow0 + r) * DD + d0 + ln] = acc[r] + bo;
}

// ---------------- in-place tanh over hidden region ----------------
__global__ void tanh_inplace_kernel(float* __restrict__ p, size_t n) {
    size_t i = ((size_t)blockIdx.x * blockDim.x + threadIdx.x) * 4;
    size_t stride = (size_t)gridDim.x * blockDim.x * 4;
    for (; i < n; i += stride) {
        float4 v = *(float4*)(p + i);
        v.x = tanhf(v.x); v.y = tanhf(v.y); v.z = tanhf(v.z); v.w = tanhf(v.w);
        *(float4*)(p + i) = v;
    }
}

extern "C" void kernel_launch(void* const* d_in, const int* in_sizes, int n_in,
                              void* d_out, int out_size, void* d_ws, size_t ws_size,
                              hipStream_t stream) {
    const float* x    = (const float*)d_in[0];  // (B,T,D)
    const float* Wx   = (const float*)d_in[1];  // (4H,D)
    const float* bx   = (const float*)d_in[2];  // (4H)
    const float* bh   = (const float*)d_in[4];  // placeholder; fixed below
    const float* Wh   = (const float*)d_in[3];  // (4H,H)
    bh = (const float*)d_in[4];                 // (4H)
    const float* Wout = (const float*)d_in[5];  // (D,H)
    const float* bout = (const float*)d_in[6];  // (D)

    float* out = (float*)d_out;                        // (B,T,D)
    float* hidden = out + (size_t)BB * TT * DD;        // (B,T,H): raw h, then tanh'd

    // workspace layout (all 16B aligned), ~11.6 MB total
    char* ws = (char*)d_ws;
    __bf16* Wxb   = (__bf16*)(ws);                     // 2 MB @ 0
    __bf16* Whb   = (__bf16*)(ws + 2097152);           // 8 MB @ 2MB
    __bf16* Wob   = (__bf16*)(ws + 10485760);          // 0.5 MB @ 10MB
    float*  bc    = (float*)(ws + 11010048);           // 16 KB
    unsigned* flg = (unsigned*)(ws + 11026432);        // 4 KB (barrier flags)
    __bf16* hping = (__bf16*)(ws + 11288576);          // 256 KB

    // weight conversions + init
    cvt_bf16_kernel<<<(GG * DD / 8 + 255) / 256, 256, 0, stream>>>(Wx, Wxb, GG * DD);
    cvt_bf16_kernel<<<(GG * HH / 8 + 255) / 256, 256, 0, stream>>>(Wh, Whb, GG * HH);
    cvt_bf16_kernel<<<(DD * HH / 8 + 255) / 256, 256, 0, stream>>>(Wout, Wob, DD * HH);
    init_misc_kernel<<<(GG + 255) / 256, 256, 0, stream>>>(bx, bh, bc, flg);

    // one persistent cooperative launch for the whole sequence
    {
        const float* xp = x;
        const __bf16* wxp = Wxb;
        const __bf16* whp = Whb;
        const float* bcp = bc;
        float* hsp = hidden;
        __bf16* hpp = hping;
        unsigned* flp = flg;
        void* kargs[] = {(void*)&xp, (void*)&wxp, (void*)&whp, (void*)&bcp,
                         (void*)&hsp, (void*)&hpp, (void*)&flp};
        hipLaunchCooperativeKernel(reinterpret_cast<void*>(lstm_seq_kernel),
                                   dim3(256), dim3(256), kargs, 0, stream);
    }

    // output head, then tanh the hidden region in place
    out_gemm_kernel<<<dim3(DD / 16, (BB * TT) / 64), 256, 0, stream>>>(
        hidden, Wob, bout, out);
    tanh_inplace_kernel<<<2048, 256, 0, stream>>>(hidden, (size_t)BB * TT * HH);
}

// Round 2
// 9981.760 us; speedup vs baseline: 3.4611x; 3.4611x over previous
//
#include <hip/hip_runtime.h>
#include <math.h>

// Problem dims
#define BB 64
#define TT 512
#define DD 256
#define HH 1024
#define GG 4096  // 4*H

typedef __bf16 bf16x8 __attribute__((ext_vector_type(8)));
typedef float floatx4 __attribute__((ext_vector_type(4)));
typedef unsigned long long u64;

// ---------------- fp32 -> bf16 conversion (weights) ----------------
__global__ void cvt_bf16_kernel(const float* __restrict__ src,
                                __bf16* __restrict__ dst, int n) {
    int i = (blockIdx.x * blockDim.x + threadIdx.x) * 8;
    if (i >= n) return;
    float4 a = *(const float4*)(src + i);
    float4 b = *(const float4*)(src + i + 4);
    bf16x8 v;
    v[0] = (__bf16)a.x; v[1] = (__bf16)a.y; v[2] = (__bf16)a.z; v[3] = (__bf16)a.w;
    v[4] = (__bf16)b.x; v[5] = (__bf16)b.y; v[6] = (__bf16)b.z; v[7] = (__bf16)b.w;
    *(bf16x8*)(dst + i) = v;
}

// ---------------- init: combined bias, zero barrier counter ----------------
__global__ void init_misc_kernel(const float* __restrict__ bx,
                                 const float* __restrict__ bh,
                                 float* __restrict__ bc,
                                 unsigned* __restrict__ cnt) {
    int i = blockIdx.x * blockDim.x + threadIdx.x;
    if (i < GG) bc[i] = bx[i] + bh[i];
    if (i < 1024) cnt[i] = 0u;
}

// ---------------- persistent LSTM over all T timesteps ----------------
// One cooperative launch: 256 blocks (j-tile of 4) x 256 threads (4 waves).
// W tile (16 packed gate rows x 1280 K) staged in LDS ONCE, reused 512x.
// Cell state register-resident. h exchanged via bf16 ping-pong using agent-scope
// RELAXED (sc1) atomics -- NO L2 writeback/invalidate fences anywhere.
// Grid barrier = one relaxed fetch_add per block + single-lane poll of one counter.
__global__ __launch_bounds__(256, 1) void lstm_seq_kernel(
    const float* __restrict__ x,      // (B,T,D) fp32
    const __bf16* __restrict__ Wxb,   // (4096,256) bf16
    const __bf16* __restrict__ Whb,   // (4096,1024) bf16
    const float* __restrict__ bc,     // (4096) combined bias
    float* __restrict__ hs,           // (B,T,H) fp32 raw h (d_out hidden region)
    __bf16* __restrict__ hping,       // 2 x (B*H) bf16 ping-pong h
    unsigned* __restrict__ cnt) {     // barrier counter (monotone)
    __shared__ __bf16 W_s[16][1288];
    __shared__ float gate_s[64][17];

    const int tid = threadIdx.x;
    const int bid = blockIdx.x;
    const int j0 = bid * 4;

    // Stage [Wx | Wh] rows for the 16 packed gate rows (ONCE).
    for (int ch = tid; ch < 2560; ch += 256) {
        int r = ch / 160;
        int pos = ch - r * 160;
        int k = pos * 8;
        int gate = r >> 2;
        int jr = r & 3;
        int gr = gate * HH + j0 + jr;
        const __bf16* src = (k < DD) ? (Wxb + (size_t)gr * DD + k)
                                     : (Whb + (size_t)gr * HH + (k - DD));
        *(uint4*)(&W_s[r][k]) = *(const uint4*)src;
    }

    const int wave = tid >> 6;
    const int lane = tid & 63;
    const int ln = lane & 15;   // A row (b within wave tile) AND B row (packed gate)
    const int q = lane >> 4;    // k-quad
    const int brow = wave * 16 + ln;

    // epilogue thread -> (b, jj); fixed for the whole sequence
    const int b2 = tid >> 2;
    const int jj = tid & 3;
    const int j = j0 + jj;
    const float bci = bc[j];
    const float bcf = bc[HH + j];
    const float bcg = bc[2 * HH + j];
    const float bco = bc[3 * HH + j];
    float creg = 0.0f;          // cell state, register-resident

    __syncthreads();            // W_s ready

    for (int t = 0; t < TT; ++t) {
        floatx4 acc = {0.f, 0.f, 0.f, 0.f};

        // ---- issue ALL h_{t-1} loads up-front (sc1, bypass stale L2),
        //      64 x 8B into registers; x-part below covers the latency ----
        u64 hreg[32][2];
        if (t > 0) {
            const u64* h64 = (const u64*)(hping +
                (size_t)((t - 1) & 1) * (BB * HH) + (size_t)brow * HH);
#pragma unroll
            for (int i = 0; i < 32; ++i) {
                hreg[i][0] = __hip_atomic_load(h64 + 8 * i + 2 * q,
                                               __ATOMIC_RELAXED,
                                               __HIP_MEMORY_SCOPE_AGENT);
                hreg[i][1] = __hip_atomic_load(h64 + 8 * i + 2 * q + 1,
                                               __ATOMIC_RELAXED,
                                               __HIP_MEMORY_SCOPE_AGENT);
            }
        }

        // x part: K = 0..255 (convert fp32 -> bf16 in-lane)
        {
            const float* xrow = x + ((size_t)brow * TT + t) * DD;
#pragma unroll
            for (int k0 = 0; k0 < DD; k0 += 32) {
                int ka = k0 + q * 8;
                float4 f0 = *(const float4*)(xrow + ka);
                float4 f1 = *(const float4*)(xrow + ka + 4);
                bf16x8 av;
                av[0] = (__bf16)f0.x; av[1] = (__bf16)f0.y;
                av[2] = (__bf16)f0.z; av[3] = (__bf16)f0.w;
                av[4] = (__bf16)f1.x; av[5] = (__bf16)f1.y;
                av[6] = (__bf16)f1.z; av[7] = (__bf16)f1.w;
                bf16x8 bv = *(const bf16x8*)(&W_s[ln][ka]);
                acc = __builtin_amdgcn_mfma_f32_16x16x32_bf16(av, bv, acc, 0, 0, 0);
            }
        }

        // h part: K = 256..1279, consume prefetched registers
        if (t > 0) {
#pragma unroll
            for (int i = 0; i < 32; ++i) {
                union { u64 u[2]; bf16x8 v; } cv;
                cv.u[0] = hreg[i][0];
                cv.u[1] = hreg[i][1];
                bf16x8 bv = *(const bf16x8*)(&W_s[ln][DD + 32 * i + 8 * q]);
                acc = __builtin_amdgcn_mfma_f32_16x16x32_bf16(cv.v, bv, acc, 0, 0, 0);
            }
        }

        // C[row=(q*4+r)][col=ln] -> LDS so each thread can gather its 4 gates
#pragma unroll
        for (int r = 0; r < 4; ++r)
            gate_s[wave * 16 + q * 4 + r][ln] = acc[r];
        __syncthreads();

        float iv = gate_s[b2][jj]      + bci;
        float fv = gate_s[b2][4 + jj]  + bcf;
        float gv = gate_s[b2][8 + jj]  + bcg;
        float ov = gate_s[b2][12 + jj] + bco;
        iv = 1.f / (1.f + expf(-iv));
        fv = 1.f / (1.f + expf(-fv));
        gv = 1.f / (1.f + expf(-gv));   // reference sigmoids the cell gate too
        ov = 1.f / (1.f + expf(-ov));
        creg = creg * fv + iv * gv;
        float hh = ov * tanhf(creg);
        hs[((size_t)b2 * TT + t) * HH + j] = hh;                         // raw h fp32

        // bf16 h for next step: agent-scope relaxed store (sc1, goes to
        // coherence point, no stale copy anywhere)
        {
            __bf16 hv = (__bf16)hh;
            unsigned short hb = __builtin_bit_cast(unsigned short, hv);
            __hip_atomic_store(
                (unsigned short*)(hping + (size_t)(t & 1) * (BB * HH) +
                                  (size_t)b2 * HH + j),
                hb, __ATOMIC_RELAXED, __HIP_MEMORY_SCOPE_AGENT);
        }

        if (t == TT - 1) break;   // no barrier needed after last step

        // ---- fence-free grid barrier ----
        // each wave: drain its h stores to the coherence point
        asm volatile("s_waitcnt vmcnt(0)" ::: "memory");
        __syncthreads();          // all 4 waves drained
        if (tid == 0) {
            __hip_atomic_fetch_add(cnt, 1u, __ATOMIC_RELAXED,
                                   __HIP_MEMORY_SCOPE_AGENT);
            const unsigned target = (unsigned)(t + 1) * 256u;
            while (__hip_atomic_load(cnt, __ATOMIC_RELAXED,
                                     __HIP_MEMORY_SCOPE_AGENT) < target)
                __builtin_amdgcn_s_sleep(2);
        }
        __syncthreads();          // fan-out; h_t globally visible (all sc1)
    }
}

// ---------------- output head: out = hs @ Wout^T + bout ----------------
// grid: (D/16, B*T/64); block tile 64 rows x 16 d-cols, K = 1024
__global__ __launch_bounds__(256) void out_gemm_kernel(
    const float* __restrict__ hs,    // (B*T, H) raw fp32
    const __bf16* __restrict__ Wob,  // (D, H) bf16
    const float* __restrict__ bout,  // (D)
    float* __restrict__ out) {       // (B*T, D)
    __shared__ __bf16 Wout_s[16][1032];
    const int tid = threadIdx.x;
    const int d0 = blockIdx.x * 16;
    const int row0 = blockIdx.y * 64;

    for (int ch = tid; ch < 2048; ch += 256) {
        int r = ch >> 7;
        int k = (ch & 127) * 8;
        *(uint4*)(&Wout_s[r][k]) = *(const uint4*)(Wob + (size_t)(d0 + r) * HH + k);
    }
    __syncthreads();

    const int wave = tid >> 6;
    const int lane = tid & 63;
    const int ln = lane & 15;
    const int q = lane >> 4;
    const int row = row0 + wave * 16 + ln;

    const float* arow = hs + (size_t)row * HH;
    floatx4 acc = {0.f, 0.f, 0.f, 0.f};
#pragma unroll 8
    for (int k0 = 0; k0 < HH; k0 += 32) {
        int ka = k0 + q * 8;
        float4 f0 = *(const float4*)(arow + ka);
        float4 f1 = *(const float4*)(arow + ka + 4);
        bf16x8 av;
        av[0] = (__bf16)f0.x; av[1] = (__bf16)f0.y;
        av[2] = (__bf16)f0.z; av[3] = (__bf16)f0.w;
        av[4] = (__bf16)f1.x; av[5] = (__bf16)f1.y;
        av[6] = (__bf16)f1.z; av[7] = (__bf16)f1.w;
        bf16x8 bv = *(const bf16x8*)(&Wout_s[ln][ka]);
        acc = __builtin_amdgcn_mfma_f32_16x16x32_bf16(av, bv, acc, 0, 0, 0);
    }
    float bo = bout[d0 + ln];
    const int orow0 = row0 + wave * 16 + q * 4;
#pragma unroll
    for (int r = 0; r < 4; ++r)
        out[(size_t)(orow0 + r) * DD + d0 + ln] = acc[r] + bo;
}

// ---------------- in-place tanh over hidden region ----------------
__global__ void tanh_inplace_kernel(float* __restrict__ p, size_t n) {
    size_t i = ((size_t)blockIdx.x * blockDim.x + threadIdx.x) * 4;
    size_t stride = (size_t)gridDim.x * blockDim.x * 4;
    for (; i < n; i += stride) {
        float4 v = *(float4*)(p + i);
        v.x = tanhf(v.x); v.y = tanhf(v.y); v.z = tanhf(v.z); v.w = tanhf(v.w);
        *(float4*)(p + i) = v;
    }
}

extern "C" void kernel_launch(void* const* d_in, const int* in_sizes, int n_in,
                              void* d_out, int out_size, void* d_ws, size_t ws_size,
                              hipStream_t stream) {
    const float* x    = (const float*)d_in[0];  // (B,T,D)
    const float* Wx   = (const float*)d_in[1];  // (4H,D)
    const float* bx   = (const float*)d_in[2];  // (4H)
    const float* Wh   = (const float*)d_in[3];  // (4H,H)
    const float* bh   = (const float*)d_in[4];  // (4H)
    const float* Wout = (const float*)d_in[5];  // (D,H)
    const float* bout = (const float*)d_in[6];  // (D)

    float* out = (float*)d_out;                        // (B,T,D)
    float* hidden = out + (size_t)BB * TT * DD;        // (B,T,H): raw h, then tanh'd

    // workspace layout (all 16B aligned), ~11.6 MB total
    char* ws = (char*)d_ws;
    __bf16* Wxb   = (__bf16*)(ws);                     // 2 MB @ 0
    __bf16* Whb   = (__bf16*)(ws + 2097152);           // 8 MB @ 2MB
    __bf16* Wob   = (__bf16*)(ws + 10485760);          // 0.5 MB @ 10MB
    float*  bc    = (float*)(ws + 11010048);           // 16 KB
    unsigned* cnt = (unsigned*)(ws + 11026432);        // 4 KB (barrier counter)
    __bf16* hping = (__bf16*)(ws + 11288576);          // 256 KB

    // weight conversions + init
    cvt_bf16_kernel<<<(GG * DD / 8 + 255) / 256, 256, 0, stream>>>(Wx, Wxb, GG * DD);
    cvt_bf16_kernel<<<(GG * HH / 8 + 255) / 256, 256, 0, stream>>>(Wh, Whb, GG * HH);
    cvt_bf16_kernel<<<(DD * HH / 8 + 255) / 256, 256, 0, stream>>>(Wout, Wob, DD * HH);
    init_misc_kernel<<<(GG + 255) / 256, 256, 0, stream>>>(bx, bh, bc, cnt);

    // one persistent cooperative launch for the whole sequence
    {
        const float* xp = x;
        const __bf16* wxp = Wxb;
        const __bf16* whp = Whb;
        const float* bcp = bc;
        float* hsp = hidden;
        __bf16* hpp = hping;
        unsigned* cnp = cnt;
        void* kargs[] = {(void*)&xp, (void*)&wxp, (void*)&whp, (void*)&bcp,
                         (void*)&hsp, (void*)&hpp, (void*)&cnp};
        hipLaunchCooperativeKernel(reinterpret_cast<void*>(lstm_seq_kernel),
                                   dim3(256), dim3(256), kargs, 0, stream);
    }

    // output head, then tanh the hidden region in place
    out_gemm_kernel<<<dim3(DD / 16, (BB * TT) / 64), 256, 0, stream>>>(
        hidden, Wob, bout, out);
    tanh_inplace_kernel<<<2048, 256, 0, stream>>>(hidden, (size_t)BB * TT * HH);
}

// Round 3
// 6016.236 us; speedup vs baseline: 5.7424x; 1.6591x over previous
//
#include <hip/hip_runtime.h>
#include <math.h>

// Problem dims
#define BB 64
#define TT 512
#define DD 256
#define HH 1024
#define GG 4096  // 4*H

typedef __bf16 bf16x8 __attribute__((ext_vector_type(8)));
typedef float floatx4 __attribute__((ext_vector_type(4)));
typedef unsigned int u32x4 __attribute__((ext_vector_type(4)));
typedef unsigned long long u64;

// ---------------- fp32 -> bf16 conversion (weights) ----------------
__global__ void cvt_bf16_kernel(const float* __restrict__ src,
                                __bf16* __restrict__ dst, int n) {
    int i = (blockIdx.x * blockDim.x + threadIdx.x) * 8;
    if (i >= n) return;
    float4 a = *(const float4*)(src + i);
    float4 b = *(const float4*)(src + i + 4);
    bf16x8 v;
    v[0] = (__bf16)a.x; v[1] = (__bf16)a.y; v[2] = (__bf16)a.z; v[3] = (__bf16)a.w;
    v[4] = (__bf16)b.x; v[5] = (__bf16)b.y; v[6] = (__bf16)b.z; v[7] = (__bf16)b.w;
    *(bf16x8*)(dst + i) = v;
}

// ---------------- init: combined bias, zero barrier flags ----------------
__global__ void init_misc_kernel(const float* __restrict__ bx,
                                 const float* __restrict__ bh,
                                 float* __restrict__ bc,
                                 unsigned* __restrict__ flags) {
    int i = blockIdx.x * blockDim.x + threadIdx.x;
    if (i < GG) bc[i] = bx[i] + bh[i];
    if (i < 1024) flags[i] = 0u;
}

// ---------------- persistent LSTM over all T timesteps ----------------
// One cooperative launch: 256 blocks (j-tile of 4) x 1024 threads (16 waves).
// 4-way K-split: wave group kg handles x[64kg,64kg+64) + h[256kg,256kg+256);
// partial gate sums land in gate_s[4][..], epilogue (tid<256) combines.
// h exchanged via bf16 ping-pong with agent-scope relaxed (sc1) ops; barrier is
// per-block flag store + wave-15 dwordx4 poll (monotone, contention-free).
__global__ __launch_bounds__(1024, 1) void lstm_seq_kernel(
    const float* __restrict__ x,      // (B,T,D) fp32
    const __bf16* __restrict__ Wxb,   // (4096,256) bf16
    const __bf16* __restrict__ Whb,   // (4096,1024) bf16
    const float* __restrict__ bc,     // (4096) combined bias
    float* __restrict__ hs,           // (B,T,H) fp32 raw h (d_out hidden region)
    __bf16* __restrict__ hping,       // 2 x (B*H) bf16 ping-pong h
    unsigned* __restrict__ flags) {   // 256 flags, monotone step counters
    __shared__ __bf16 W_s[16][1288];
    __shared__ float gate_s[4][64][17];

    const int tid = threadIdx.x;
    const int bid = blockIdx.x;
    const int j0 = bid * 4;

    // Stage [Wx | Wh] rows for the 16 packed gate rows (ONCE).
    for (int ch = tid; ch < 2560; ch += 1024) {
        int r = ch / 160;
        int pos = ch - r * 160;
        int k = pos * 8;
        int gate = r >> 2;
        int jr = r & 3;
        int gr = gate * HH + j0 + jr;
        const __bf16* src = (k < DD) ? (Wxb + (size_t)gr * DD + k)
                                     : (Whb + (size_t)gr * HH + (k - DD));
        *(uint4*)(&W_s[r][k]) = *(const uint4*)src;
    }

    const int wave = tid >> 6;
    const int lane = tid & 63;
    const int kg = wave >> 2;       // K-group 0..3
    const int bw = wave & 3;        // batch quarter
    const int ln = lane & 15;       // A row (b) AND B row (packed gate)
    const int q = lane >> 4;        // k-quad
    const int brow = bw * 16 + ln;
    const int xk0 = kg * 64;        // this group's x K-range start
    const int hk0 = kg * 256;       // this group's h K-range start

    // epilogue thread -> (b, jj)
    const int b2 = tid >> 2;        // valid for tid<256
    const int jj = tid & 3;
    const int j = j0 + jj;
    const float bci = bc[j];
    const float bcf = bc[HH + j];
    const float bcg = bc[2 * HH + j];
    const float bco = bc[3 * HH + j];
    float creg = 0.0f;              // cell state, register-resident (tid<256)

    __syncthreads();                // W_s ready

    for (int t = 0; t < TT; ++t) {
        floatx4 acc = {0.f, 0.f, 0.f, 0.f};

        // ---- x part: this group's 64 K (2 chunks); overlaps barrier poll ----
        {
            const float* xrow = x + ((size_t)brow * TT + t) * DD;
#pragma unroll
            for (int i = 0; i < 2; ++i) {
                int ka = xk0 + 32 * i + q * 8;
                float4 f0 = *(const float4*)(xrow + ka);
                float4 f1 = *(const float4*)(xrow + ka + 4);
                bf16x8 av;
                av[0] = (__bf16)f0.x; av[1] = (__bf16)f0.y;
                av[2] = (__bf16)f0.z; av[3] = (__bf16)f0.w;
                av[4] = (__bf16)f1.x; av[5] = (__bf16)f1.y;
                av[6] = (__bf16)f1.z; av[7] = (__bf16)f1.w;
                bf16x8 bv = *(const bf16x8*)(&W_s[ln][ka]);
                acc = __builtin_amdgcn_mfma_f32_16x16x32_bf16(av, bv, acc, 0, 0, 0);
            }
        }

        if (t > 0) {
            // ---- barrier poll: wave 15 waits for all blocks @ step t-1 done ----
            if (tid >= 960) {
                const unsigned tgt = (unsigned)t;
                const u32x4* fp = (const u32x4*)flags + (tid - 960);
                for (;;) {
                    u32x4 v;
                    asm volatile(
                        "global_load_dwordx4 %0, %1, off sc1\n\t"
                        "s_waitcnt vmcnt(0)"
                        : "=v"(v) : "v"(fp) : "memory");
                    bool ok = (v[0] >= tgt) && (v[1] >= tgt) &&
                              (v[2] >= tgt) && (v[3] >= tgt);
                    if (__all((int)ok)) break;
                    __builtin_amdgcn_s_sleep(1);
                }
            }
            __syncthreads();        // h_{t-1} globally visible for all waves

            // ---- h part: this group's 256 K (8 chunks), loads issued first ----
            const __bf16* hrow = hping + (size_t)((t - 1) & 1) * (BB * HH) +
                                 (size_t)brow * HH;
            const u64* p64 = (const u64*)(hrow + hk0 + q * 8);
            u64 hreg[8][2];
#pragma unroll
            for (int i = 0; i < 8; ++i) {
                hreg[i][0] = __hip_atomic_load(p64 + 8 * i, __ATOMIC_RELAXED,
                                               __HIP_MEMORY_SCOPE_AGENT);
                hreg[i][1] = __hip_atomic_load(p64 + 8 * i + 1, __ATOMIC_RELAXED,
                                               __HIP_MEMORY_SCOPE_AGENT);
            }
#pragma unroll
            for (int i = 0; i < 8; ++i) {
                union { u64 u[2]; bf16x8 v; } cv;
                cv.u[0] = hreg[i][0];
                cv.u[1] = hreg[i][1];
                bf16x8 bv = *(const bf16x8*)(&W_s[ln][DD + hk0 + 32 * i + q * 8]);
                acc = __builtin_amdgcn_mfma_f32_16x16x32_bf16(cv.v, bv, acc, 0, 0, 0);
            }
        }

        // partial C[row=(q*4+r)][col=ln] for this K-group
#pragma unroll
        for (int r = 0; r < 4; ++r)
            gate_s[kg][bw * 16 + q * 4 + r][ln] = acc[r];
        __syncthreads();

        // ---- epilogue: combine 4 partials, activations, state update ----
        if (tid < 256) {
            float iv = gate_s[0][b2][jj] + gate_s[1][b2][jj] +
                       gate_s[2][b2][jj] + gate_s[3][b2][jj] + bci;
            float fv = gate_s[0][b2][4 + jj] + gate_s[1][b2][4 + jj] +
                       gate_s[2][b2][4 + jj] + gate_s[3][b2][4 + jj] + bcf;
            float gv = gate_s[0][b2][8 + jj] + gate_s[1][b2][8 + jj] +
                       gate_s[2][b2][8 + jj] + gate_s[3][b2][8 + jj] + bcg;
            float ov = gate_s[0][b2][12 + jj] + gate_s[1][b2][12 + jj] +
                       gate_s[2][b2][12 + jj] + gate_s[3][b2][12 + jj] + bco;
            iv = 1.f / (1.f + expf(-iv));
            fv = 1.f / (1.f + expf(-fv));
            gv = 1.f / (1.f + expf(-gv));   // reference sigmoids the cell gate
            ov = 1.f / (1.f + expf(-ov));
            creg = creg * fv + iv * gv;
            float hh = ov * tanhf(creg);

            // gather the quad (4 consecutive j) via shfl; lane jj==0 stores
            int base = lane & ~3;
            float h0 = __shfl(hh, base);
            float h1 = __shfl(hh, base + 1);
            float h2 = __shfl(hh, base + 2);
            float h3 = __shfl(hh, base + 3);
            if (jj == 0) {
                float4 f4 = {h0, h1, h2, h3};
                *(float4*)(hs + ((size_t)b2 * TT + t) * HH + j0) = f4;
                unsigned short s0 = __builtin_bit_cast(unsigned short, (__bf16)h0);
                unsigned short s1 = __builtin_bit_cast(unsigned short, (__bf16)h1);
                unsigned short s2 = __builtin_bit_cast(unsigned short, (__bf16)h2);
                unsigned short s3 = __builtin_bit_cast(unsigned short, (__bf16)h3);
                u64 pk = (u64)s0 | ((u64)s1 << 16) | ((u64)s2 << 32) |
                         ((u64)s3 << 48);
                __hip_atomic_store(
                    (u64*)(hping + (size_t)(t & 1) * (BB * HH) +
                           (size_t)b2 * HH + j0),
                    pk, __ATOMIC_RELAXED, __HIP_MEMORY_SCOPE_AGENT);
            }
        }

        if (t == TT - 1) break;

        // ---- arrival: drain stores to coherence point, then flag this block ----
        asm volatile("s_waitcnt vmcnt(0)" ::: "memory");
        __syncthreads();            // all waves drained
        if (tid == 0)
            __hip_atomic_store(flags + bid, (unsigned)(t + 1),
                               __ATOMIC_RELAXED, __HIP_MEMORY_SCOPE_AGENT);
    }
}

// ---------------- output head: out = hs @ Wout^T + bout ----------------
// grid: (D/16, B*T/64); block tile 64 rows x 16 d-cols, K = 1024
__global__ __launch_bounds__(256) void out_gemm_kernel(
    const float* __restrict__ hs,    // (B*T, H) raw fp32
    const __bf16* __restrict__ Wob,  // (D, H) bf16
    const float* __restrict__ bout,  // (D)
    float* __restrict__ out) {       // (B*T, D)
    __shared__ __bf16 Wout_s[16][1032];
    const int tid = threadIdx.x;
    const int d0 = blockIdx.x * 16;
    const int row0 = blockIdx.y * 64;

    for (int ch = tid; ch < 2048; ch += 256) {
        int r = ch >> 7;
        int k = (ch & 127) * 8;
        *(uint4*)(&Wout_s[r][k]) = *(const uint4*)(Wob + (size_t)(d0 + r) * HH + k);
    }
    __syncthreads();

    const int wave = tid >> 6;
    const int lane = tid & 63;
    const int ln = lane & 15;
    const int q = lane >> 4;
    const int row = row0 + wave * 16 + ln;

    const float* arow = hs + (size_t)row * HH;
    floatx4 acc = {0.f, 0.f, 0.f, 0.f};
#pragma unroll 8
    for (int k0 = 0; k0 < HH; k0 += 32) {
        int ka = k0 + q * 8;
        float4 f0 = *(const float4*)(arow + ka);
        float4 f1 = *(const float4*)(arow + ka + 4);
        bf16x8 av;
        av[0] = (__bf16)f0.x; av[1] = (__bf16)f0.y;
        av[2] = (__bf16)f0.z; av[3] = (__bf16)f0.w;
        av[4] = (__bf16)f1.x; av[5] = (__bf16)f1.y;
        av[6] = (__bf16)f1.z; av[7] = (__bf16)f1.w;
        bf16x8 bv = *(const bf16x8*)(&Wout_s[ln][ka]);
        acc = __builtin_amdgcn_mfma_f32_16x16x32_bf16(av, bv, acc, 0, 0, 0);
    }
    float bo = bout[d0 + ln];
    const int orow0 = row0 + wave * 16 + q * 4;
#pragma unroll
    for (int r = 0; r < 4; ++r)
        out[(size_t)(orow0 + r) * DD + d0 + ln] = acc[r] + bo;
}

// ---------------- in-place tanh over hidden region ----------------
__global__ void tanh_inplace_kernel(float* __restrict__ p, size_t n) {
    size_t i = ((size_t)blockIdx.x * blockDim.x + threadIdx.x) * 4;
    size_t stride = (size_t)gridDim.x * blockDim.x * 4;
    for (; i < n; i += stride) {
        float4 v = *(float4*)(p + i);
        v.x = tanhf(v.x); v.y = tanhf(v.y); v.z = tanhf(v.z); v.w = tanhf(v.w);
        *(float4*)(p + i) = v;
    }
}

extern "C" void kernel_launch(void* const* d_in, const int* in_sizes, int n_in,
                              void* d_out, int out_size, void* d_ws, size_t ws_size,
                              hipStream_t stream) {
    const float* x    = (const float*)d_in[0];  // (B,T,D)
    const float* Wx   = (const float*)d_in[1];  // (4H,D)
    const float* bx   = (const float*)d_in[2];  // (4H)
    const float* Wh   = (const float*)d_in[3];  // (4H,H)
    const float* bh   = (const float*)d_in[4];  // (4H)
    const float* Wout = (const float*)d_in[5];  // (D,H)
    const float* bout = (const float*)d_in[6];  // (D)

    float* out = (float*)d_out;                        // (B,T,D)
    float* hidden = out + (size_t)BB * TT * DD;        // (B,T,H): raw h, then tanh'd

    // workspace layout (all 16B aligned), ~11.6 MB total
    char* ws = (char*)d_ws;
    __bf16* Wxb   = (__bf16*)(ws);                     // 2 MB @ 0
    __bf16* Whb   = (__bf16*)(ws + 2097152);           // 8 MB @ 2MB
    __bf16* Wob   = (__bf16*)(ws + 10485760);          // 0.5 MB @ 10MB
    float*  bc    = (float*)(ws + 11010048);           // 16 KB
    unsigned* flg = (unsigned*)(ws + 11026432);        // 1 KB (barrier flags)
    __bf16* hping = (__bf16*)(ws + 11288576);          // 256 KB

    // weight conversions + init
    cvt_bf16_kernel<<<(GG * DD / 8 + 255) / 256, 256, 0, stream>>>(Wx, Wxb, GG * DD);
    cvt_bf16_kernel<<<(GG * HH / 8 + 255) / 256, 256, 0, stream>>>(Wh, Whb, GG * HH);
    cvt_bf16_kernel<<<(DD * HH / 8 + 255) / 256, 256, 0, stream>>>(Wout, Wob, DD * HH);
    init_misc_kernel<<<(GG + 255) / 256, 256, 0, stream>>>(bx, bh, bc, flg);

    // one persistent cooperative launch for the whole sequence
    {
        const float* xp = x;
        const __bf16* wxp = Wxb;
        const __bf16* whp = Whb;
        const float* bcp = bc;
        float* hsp = hidden;
        __bf16* hpp = hping;
        unsigned* flp = flg;
        void* kargs[] = {(void*)&xp, (void*)&wxp, (void*)&whp, (void*)&bcp,
                         (void*)&hsp, (void*)&hpp, (void*)&flp};
        hipLaunchCooperativeKernel(reinterpret_cast<void*>(lstm_seq_kernel),
                                   dim3(256), dim3(1024), kargs, 0, stream);
    }

    // output head, then tanh the hidden region in place
    out_gemm_kernel<<<dim3(DD / 16, (BB * TT) / 64), 256, 0, stream>>>(
        hidden, Wob, bout, out);
    tanh_inplace_kernel<<<2048, 256, 0, stream>>>(hidden, (size_t)BB * TT * HH);
}